// Round 1
// baseline (349.716 us; speedup 1.0000x reference)
//
#include <hip/hip_runtime.h>

// x shape (B, T, A, D) = (256, 2048, 22, 2) fp32
#define BB 256
#define TT 2048
#define AD 44                 // A*D
#define AD4 11                // float4 chunks per (b,t) row
#define F4_PER_B (TT * AD4)   // 22528 float4 per batch
#define ELEMS 8               // float4 per thread
#define BLK_F4 (256 * ELEMS)  // 2048 float4 per block = F4_PER_B / 11
#define BLOCKS_PER_B 11
#define NBLK (BB * BLOCKS_PER_B)  // 2816 blocks

typedef float v4 __attribute__((ext_vector_type(4)));

// Fused streaming copy + NaN-range detection + gap interpolation.
// Each block covers 2048 consecutive float4 = 1/11 of one batch (b is
// block-uniform). NaN chunks (== gap-interior rows, which are entirely NaN)
// are NOT stored by the streaming pass; the last-arriving block of each
// batch (per-batch arrival counter) writes the interpolated gap instead.
// This removes the second dispatch and the double-write of the gap region.
__global__ __launch_bounds__(256) void scan_fix(const v4* __restrict__ x4,
                                                v4* __restrict__ out4,
                                                unsigned* __restrict__ mn,
                                                unsigned* __restrict__ mxk,
                                                unsigned* __restrict__ cnt) {
  const int tid = threadIdx.x;
  const int b = blockIdx.x / BLOCKS_PER_B;
  const int blk_in_b = blockIdx.x - b * BLOCKS_PER_B;
  const int base_in_b = blk_in_b * BLK_F4;          // float4 offset within batch
  const size_t base = (size_t)b * F4_PER_B + base_in_b;

  // Issue all 8 loads first (independent -> 8 outstanding vmem ops).
  v4 v[ELEMS];
#pragma unroll
  for (int k = 0; k < ELEMS; ++k) {
    v[k] = __builtin_nontemporal_load(&x4[base + k * 256 + tid]);
  }

  int tmin = TT;
  int tmax = -1;
#pragma unroll
  for (int k = 0; k < ELEMS; ++k) {
    const int off = k * 256 + tid;
    const v4 w = v[k];
    const bool n = (w.x != w.x) || (w.y != w.y) || (w.z != w.z) || (w.w != w.w);
    if (!n) {
      // Streaming store, no reuse: bypass L2 write-allocate.
      __builtin_nontemporal_store(w, &out4[base + off]);
    } else {
      // NaN chunk -> gap-interior row; fixer block writes it later.
      const int t = (base_in_b + off) / AD4;        // magic-mul const div
      tmin = min(tmin, t);
      tmax = max(tmax, t);
    }
  }

  const unsigned long long m = __ballot(tmax >= 0);
  if (m != 0ull) {                                  // wave-uniform, rare
#pragma unroll
    for (int d = 32; d > 0; d >>= 1) {
      tmin = min(tmin, __shfl_xor(tmin, d));
      tmax = max(tmax, __shfl_xor(tmax, d));
    }
    if ((tid & 63) == 0) {
      atomicMin(&mn[b], (unsigned)tmin);
      atomicMin(&mxk[b], (unsigned)(4096 - tmax));
    }
  }

  // ---- arrival counter: last block of this batch becomes the fixer ----
  __shared__ unsigned fix_flag;
  __syncthreads();                 // all waves' atomicMins issued & drained
  if (tid == 0) {
    __threadfence();               // release: mins visible before arrival
    // cnt[b] memset to 0xFFFFFFFF; 11 arrivals return -1,0,1,...,9.
    const unsigned old = atomicAdd(&cnt[b], 1u);
    fix_flag = (old == (unsigned)(BLOCKS_PER_B - 2));  // == 9 -> last
  }
  __syncthreads();
  if (!fix_flag) return;

  // ---- gap fix (whole block) ----
  __shared__ int s_sh, e_sh;
  __shared__ v4 sxs[AD4], sxe[AD4];
  if (tid == 0) {
    __threadfence();               // acquire side of the counter handoff
    const unsigned mnv = __hip_atomic_load(&mn[b], __ATOMIC_ACQUIRE,
                                           __HIP_MEMORY_SCOPE_AGENT);
    const unsigned mxv = __hip_atomic_load(&mxk[b], __ATOMIC_ACQUIRE,
                                           __HIP_MEMORY_SCOPE_AGENT);
    s_sh = (int)mnv - 1;           // index before first NaN
    e_sh = (4096 - (int)mxv) + 1;  // index after last NaN
  }
  __syncthreads();
  const int s = s_sh;
  const int e = e_sh;

  const size_t bbase = (size_t)b * F4_PER_B;
  if (tid < AD4) sxs[tid] = x4[bbase + (size_t)s * AD4 + tid];
  if (tid >= 64 && tid < 64 + AD4) sxe[tid - 64] = x4[bbase + (size_t)e * AD4 + (tid - 64)];
  __syncthreads();

  const float inv = 1.0f / (float)(e - s);
  const int total = (e - s - 1) * AD4;          // float4s in the gap
  for (int i = tid; i < total; i += 256) {
    const int dt = i / AD4;
    const int c = i - dt * AD4;
    const int t = s + 1 + dt;
    const float w = (float)(dt + 1) * inv;      // (t - s)/(e - s)
    const float om = 1.0f - w;
    const v4 a = sxs[c];
    const v4 z = sxe[c];
    v4 r;
    r.x = a.x * om + z.x * w;
    r.y = a.y * om + z.y * w;
    r.z = a.z * om + z.z * w;
    r.w = a.w * om + z.w * w;
    out4[bbase + (size_t)t * AD4 + c] = r;
  }
}

extern "C" void kernel_launch(void* const* d_in, const int* in_sizes, int n_in,
                              void* d_out, int out_size, void* d_ws, size_t ws_size,
                              hipStream_t stream) {
  const v4* x4 = (const v4*)d_in[0];
  v4* out4 = (v4*)d_out;

  // ws layout: [0,1KB) mn, [1KB,2KB) mxk, [2KB,3KB) cnt  (256 u32 each)
  unsigned* mn = (unsigned*)d_ws;
  unsigned* mxk = (unsigned*)((char*)d_ws + 1024);
  unsigned* cnt = (unsigned*)((char*)d_ws + 2048);

  // 0xFF bytes == 0xFFFFFFFF words: init for atomicMin targets AND the
  // arrival counters (counter arrivals return -1,0,...,9; last == 9).
  hipMemsetAsync(d_ws, 0xFF, 3072, stream);

  scan_fix<<<NBLK, 256, 0, stream>>>(x4, out4, mn, mxk, cnt);
}

// Round 2
// 166.499 us; speedup vs baseline: 2.1004x; 2.1004x over previous
//
#include <hip/hip_runtime.h>

// x shape (B, T, A, D) = (256, 2048, 22, 2) fp32
#define BB 256
#define TT 2048
#define AD4 11                       // float4 chunks per (b,t) row
#define F4_PER_B (TT * AD4)          // 22528 float4 per batch
#define NTHREADS 1024                // 16 waves; block == one batch
#define HALF 11                      // float4 per thread per half (2*11*1024 = 22528)
#define NWAVES (NTHREADS / 64)

typedef float v4 __attribute__((ext_vector_type(4)));

// One block per batch: streaming copy + NaN-range detect + gap interpolation,
// all in-block. No cross-block handoff -> no device-scope fences (the round-1
// threadfence-per-block cost ~200us in L2 writeback serialization), no
// workspace, no memset dispatch, no second dispatch.
// NaN chunks (gap-interior rows are all-NaN) are not stored by the streaming
// pass; the fix phase after __syncthreads() writes the gap exactly once.
__global__ __launch_bounds__(NTHREADS) void interp_fused(
    const v4* __restrict__ x4, v4* __restrict__ out4) {
  const int tid = threadIdx.x;
  const int b = blockIdx.x;
  const size_t base = (size_t)b * F4_PER_B;

  int tmin = TT;
  int tmax = -1;

  // Two halves of 11 float4/thread: issue all 11 loads (independent, 11
  // outstanding vmem ops), then store. Working set 44 VGPRs/half keeps the
  // kernel under the 128-VGPR cap required for a 16-wave block.
#pragma unroll
  for (int h = 0; h < 2; ++h) {
    const int hbase = h * (HALF * NTHREADS);
    v4 v[HALF];
#pragma unroll
    for (int k = 0; k < HALF; ++k) {
      v[k] = x4[base + hbase + k * NTHREADS + tid];
    }
#pragma unroll
    for (int k = 0; k < HALF; ++k) {
      const int off = hbase + k * NTHREADS + tid;
      const v4 w = v[k];
      const bool n = (w.x != w.x) || (w.y != w.y) || (w.z != w.z) || (w.w != w.w);
      if (!n) {
        out4[base + off] = w;
      } else {
        const int t = off / AD4;               // magic-mul const div
        tmin = min(tmin, t);
        tmax = max(tmax, t);
      }
    }
  }

  // Wave reduce (64 lanes) ...
#pragma unroll
  for (int d = 32; d > 0; d >>= 1) {
    tmin = min(tmin, __shfl_xor(tmin, d));
    tmax = max(tmax, __shfl_xor(tmax, d));
  }

  // ... then cross-wave reduce in LDS.
  __shared__ int smin[NWAVES], smax[NWAVES];
  __shared__ int s_sh, e_sh;
  const int wid = tid >> 6;
  if ((tid & 63) == 0) {
    smin[wid] = tmin;
    smax[wid] = tmax;
  }
  __syncthreads();
  if (tid == 0) {
    int a = TT, z = -1;
#pragma unroll
    for (int i = 0; i < NWAVES; ++i) {
      a = min(a, smin[i]);
      z = max(z, smax[i]);
    }
    if (z < 0) {            // defensive: no NaN in this batch
      s_sh = 0;
      e_sh = 1;             // total = 0 -> fix loop no-ops; reads stay in-bounds
    } else {
      s_sh = a - 1;         // index before first NaN row
      e_sh = z + 1;         // index after last NaN row
    }
  }
  __syncthreads();
  const int s = s_sh;
  const int e = e_sh;

  // Boundary rows -> LDS (both rows are NaN-free by construction).
  __shared__ v4 sxs[AD4], sxe[AD4];
  if (tid < AD4) sxs[tid] = x4[base + (size_t)s * AD4 + tid];
  if (tid >= 64 && tid < 64 + AD4) sxe[tid - 64] = x4[base + (size_t)e * AD4 + (tid - 64)];
  __syncthreads();

  // Interpolate the gap interior (rows s+1 .. e-1), written exactly once.
  const float inv = 1.0f / (float)(e - s);
  const int total = (e - s - 1) * AD4;         // float4s in the gap
  for (int i = tid; i < total; i += NTHREADS) {
    const int dt = i / AD4;
    const int c = i - dt * AD4;
    const int t = s + 1 + dt;
    const float w = (float)(dt + 1) * inv;     // (t - s)/(e - s)
    const float om = 1.0f - w;
    const v4 a = sxs[c];
    const v4 z = sxe[c];
    v4 r;
    r.x = a.x * om + z.x * w;
    r.y = a.y * om + z.y * w;
    r.z = a.z * om + z.z * w;
    r.w = a.w * om + z.w * w;
    out4[base + (size_t)t * AD4 + c] = r;
  }
}

extern "C" void kernel_launch(void* const* d_in, const int* in_sizes, int n_in,
                              void* d_out, int out_size, void* d_ws, size_t ws_size,
                              hipStream_t stream) {
  const v4* x4 = (const v4*)d_in[0];
  v4* out4 = (v4*)d_out;
  interp_fused<<<BB, NTHREADS, 0, stream>>>(x4, out4);
}